// Round 2
// baseline (284.970 us; speedup 1.0000x reference)
//
#include <hip/hip_runtime.h>

// LightningAttention on MI355X — round 2: fp32 in/out (reference dtypes), fused 3-kernel.
// B=8 T=8192 DM=128 H=8 Dh=16.
// k0: zero ctx/ksum in ws (68KB only)
// k1: [k|v] GEMM (64 rows/block, LDS-tiled) -> rope+elu+1(k) -> partial ctx/ksum atomicAdd
// k2: q GEMM -> rope+elu+1 -> per-head (q'C)*z -> O^T in LDS (row-permuted) -> @Wo+bo -> out

constexpr int Tn = 8192;

// ---------------- kernel 0: zero ctx/ksum ----------------
__global__ void k_init(float* __restrict__ ctx_zero) {
  int gid = blockIdx.x * 256 + threadIdx.x;
  if (gid < 8 * 8 * 16 * 16 + 8 * 8 * 16) ctx_zero[gid] = 0.0f;  // ctx + ksum contiguous
}

__device__ __forceinline__ void stage_rope(int tid, int t0, float rc[64][8], float rs[64][8]) {
#pragma unroll
  for (int p = 0; p < 2; ++p) {
    int idx = tid + p * 256;
    int r = idx >> 3, j = idx & 7;
    float invf = 1.0f / powf(10000.0f, (float)j * 0.125f);  // mirror ref: 1/10000**(j/8)
    float arg = (float)(t0 + r) * invf;
    float s, c;
    sincosf(arg, &s, &c);
    rc[r][j] = c;
    rs[r][j] = s;
  }
}

// ---------------- kernel 1: k,v GEMM + rope/elu(k) + context partials ----------------
__global__ __launch_bounds__(256, 2) void k_kv_ctx(
    const float* __restrict__ x,
    const float* __restrict__ Wk, const float* __restrict__ bk,
    const float* __restrict__ Wv, const float* __restrict__ bv,
    float* __restrict__ ctx, float* __restrict__ ksum) {
  // phase1 staging: xs[32][68] (2176) + ws[32][256] (8192) = 10368 f
  // phase2: kS [64][128] (8192 f) + vS [64][128] (8192 f)
  __shared__ __align__(16) float smem[16384];            // 64 KB
  __shared__ float rc[64][8], rs[64][8];                 // 4 KB
  const int tid = threadIdx.x;
  const int row0 = blockIdx.x * 64;
  const int b = row0 >> 13;
  const int t0 = row0 & (Tn - 1);

  stage_rope(tid, t0, rc, rs);   // first use is after in-loop syncthreads

  const int tc = tid & 31, tr = tid >> 5;
  const int c0 = tc * 4, r0 = tr * 8;           // thread tile: 8 rows x (4 k-cols + 4 v-cols)
  float acc[8][8];
#pragma unroll
  for (int i = 0; i < 8; ++i)
#pragma unroll
    for (int j = 0; j < 8; ++j) acc[i][j] = 0.f;

  float* xs = smem;          // [32][68] x^T chunk
  float* ws = smem + 2176;   // [32][256] [Wk|Wv] chunk

#pragma unroll 1
  for (int kb = 0; kb < 4; ++kb) {
    {  // stage x^T: 8 floats per thread
      int r = tid >> 2, kg = (tid & 3) * 8;
      const float* xp = x + (size_t)(row0 + r) * 128 + kb * 32 + kg;
      float4 a = *(const float4*)xp;
      float4 b4 = *(const float4*)(xp + 4);
      float v[8] = {a.x, a.y, a.z, a.w, b4.x, b4.y, b4.z, b4.w};
#pragma unroll
      for (int i = 0; i < 8; ++i) xs[(kg + i) * 68 + r] = v[i];
    }
#pragma unroll
    for (int p = 0; p < 4; ++p) {  // stage [Wk|Wv]
      int idx = tid + p * 256;
      int kk = idx >> 5, c8 = (idx & 31) * 8;
      const float* pw = (c8 < 128) ? (Wk + (size_t)(kb * 32 + kk) * 128 + c8)
                                   : (Wv + (size_t)(kb * 32 + kk) * 128 + (c8 - 128));
      float4 a = *(const float4*)pw;
      float4 b4 = *(const float4*)(pw + 4);
      float* dst = ws + kk * 256 + c8;
      *(float4*)dst = a;
      *(float4*)(dst + 4) = b4;
    }
    __syncthreads();
#pragma unroll 8
    for (int kk = 0; kk < 32; ++kk) {
      float4 xa = *(const float4*)(xs + kk * 68 + r0);
      float4 xb = *(const float4*)(xs + kk * 68 + r0 + 4);
      float4 wa = *(const float4*)(ws + kk * 256 + c0);
      float4 wb = *(const float4*)(ws + kk * 256 + 128 + c0);
      float xv[8] = {xa.x, xa.y, xa.z, xa.w, xb.x, xb.y, xb.z, xb.w};
      float wv[8] = {wa.x, wa.y, wa.z, wa.w, wb.x, wb.y, wb.z, wb.w};
#pragma unroll
      for (int i = 0; i < 8; ++i)
#pragma unroll
        for (int j = 0; j < 8; ++j) acc[i][j] += xv[i] * wv[j];
    }
    __syncthreads();
  }

  // epilogue: bias, write k and v tiles to LDS (fp32)
  float4 bkf = *(const float4*)(bk + c0);
  float4 bvf = *(const float4*)(bv + c0);
  float* kS = smem;          // [64][128]
  float* vS = smem + 8192;   // [64][128]
#pragma unroll
  for (int i = 0; i < 8; ++i) {
    int r = r0 + i;
    float4 kq, vq;
    kq.x = acc[i][0] + bkf.x; kq.y = acc[i][1] + bkf.y;
    kq.z = acc[i][2] + bkf.z; kq.w = acc[i][3] + bkf.w;
    vq.x = acc[i][4] + bvf.x; vq.y = acc[i][5] + bvf.y;
    vq.z = acc[i][6] + bvf.z; vq.w = acc[i][7] + bvf.w;
    *(float4*)(kS + r * 128 + c0) = kq;
    *(float4*)(vS + r * 128 + c0) = vq;
  }
  __syncthreads();

  // rope + elu+1 on k, in place (pairs (d, d+8) within a head)
  {
    int r = tid >> 2, jq = tid & 3;
#pragma unroll
    for (int hh = 0; hh < 2; ++hh) {
      int h = jq * 2 + hh;
      float* kr = kS + r * 128 + h * 16;
#pragma unroll
      for (int d = 0; d < 8; ++d) {
        float a = kr[d], bb = kr[d + 8];
        float cc = rc[r][d], ss = rs[r][d];
        float n1 = a * cc - bb * ss;
        float n2 = a * ss + bb * cc;
        kr[d]     = (n1 > 0.f) ? (n1 + 1.f) : __expf(n1);  // elu(x)+1
        kr[d + 8] = (n2 > 0.f) ? (n2 + 1.f) : __expf(n2);
      }
    }
  }
  __syncthreads();

  // context partials: thread -> (h, d, e0..e0+7); reduce 64 rows then atomicAdd
  {
    int h = tid >> 5, d = (tid & 31) >> 1, e0 = (tid & 1) * 8;
    float ca[8];
#pragma unroll
    for (int j = 0; j < 8; ++j) ca[j] = 0.f;
    float ksacc = 0.f;
#pragma unroll 4
    for (int r = 0; r < 64; ++r) {
      float kd = kS[r * 128 + h * 16 + d];
      const float* vp = vS + r * 128 + h * 16 + e0;
      float4 v0 = *(const float4*)vp;
      float4 v1 = *(const float4*)(vp + 4);
      ca[0] += kd * v0.x; ca[1] += kd * v0.y; ca[2] += kd * v0.z; ca[3] += kd * v0.w;
      ca[4] += kd * v1.x; ca[5] += kd * v1.y; ca[6] += kd * v1.z; ca[7] += kd * v1.w;
      ksacc += kd;
    }
    float* cp = ctx + ((size_t)(b * 8 + h) * 16 + d) * 16 + e0;
#pragma unroll
    for (int j = 0; j < 8; ++j) atomicAdd(cp + j, ca[j]);
    if (e0 == 0) atomicAdd(ksum + (b * 8 + h) * 16 + d, ksacc);
  }
}

// ---------------- kernel 2: q GEMM + rope/elu + apply + @Wo ----------------
__global__ __launch_bounds__(256, 2) void k_q_attn_o(
    const float* __restrict__ x,
    const float* __restrict__ Wq, const float* __restrict__ bq,
    const float* __restrict__ Wo, const float* __restrict__ bo,
    const float* __restrict__ ctx, const float* __restrict__ ksum,
    float* __restrict__ out) {
  __shared__ __align__(16) float otF[128 * 68];  // O^T (rows permuted m=e*8+h); Phase A alias: xs[32][68]
  __shared__ __align__(16) float wqs[5120];      // Phase A: Wq [32][8*20]; Phase C: Wo [32][128]
  __shared__ float ctxs[8 * 260];                // per-head pad 4 -> conflict-free reads
  __shared__ float ksums[160];                   // stride 20 per head
  __shared__ float rc[64][8], rs[64][8];
  const int tid = threadIdx.x;
  const int row0 = blockIdx.x * 64;
  const int b = row0 >> 13;
  const int t0 = row0 & (Tn - 1);

  stage_rope(tid, t0, rc, rs);
  {  // stage ctx (head-padded) + ksum
    int h = tid >> 5, w8 = (tid & 31) * 8;
    const float* src = ctx + (size_t)(b * 8 + h) * 256 + w8;
    float4 a0 = *(const float4*)src;
    float4 a1 = *(const float4*)(src + 4);
    *(float4*)(ctxs + h * 260 + w8) = a0;
    *(float4*)(ctxs + h * 260 + w8 + 4) = a1;
    if (tid < 32) {
#pragma unroll
      for (int j = 0; j < 4; ++j) {
        int idx = tid * 4 + j;
        ksums[(idx >> 4) * 20 + (idx & 15)] = ksum[b * 128 + idx];
      }
    }
  }

  // ---- Phase A: q = x @ Wq (thread tile: 2 rows x 16 cols = one full head) ----
  const int h = tid & 7;
  const int r0 = (tid >> 3) * 2;
  float qa[2][16];
#pragma unroll
  for (int i = 0; i < 2; ++i)
#pragma unroll
    for (int d = 0; d < 16; ++d) qa[i][d] = 0.f;
  float* xs = otF;  // [32][68]

#pragma unroll 1
  for (int kb = 0; kb < 4; ++kb) {
    {  // stage x^T
      int r = tid >> 2, kg = (tid & 3) * 8;
      const float* xp = x + (size_t)(row0 + r) * 128 + kb * 32 + kg;
      float4 a = *(const float4*)xp;
      float4 b4 = *(const float4*)(xp + 4);
      float v[8] = {a.x, a.y, a.z, a.w, b4.x, b4.y, b4.z, b4.w};
#pragma unroll
      for (int i = 0; i < 8; ++i) xs[(kg + i) * 68 + r] = v[i];
    }
#pragma unroll
    for (int p = 0; p < 2; ++p) {  // stage Wq head-padded [32][h*20+d]
      int idx = tid + p * 256;
      int kk = idx >> 4, c8 = (idx & 15) * 8;
      int hh = c8 >> 4, dd = c8 & 15;
      const float* pw = Wq + (size_t)(kb * 32 + kk) * 128 + c8;
      float4 a = *(const float4*)pw;
      float4 b4 = *(const float4*)(pw + 4);
      float* dst = wqs + kk * 160 + hh * 20 + dd;
      *(float4*)dst = a;            // dd in {0,8} -> 16B aligned within 20-stride head slot
      *(float4*)(dst + 4) = b4;
    }
    __syncthreads();
#pragma unroll 8
    for (int kk = 0; kk < 32; ++kk) {
      float2 xv = *(const float2*)(xs + kk * 68 + r0);
      const float* wp = wqs + kk * 160 + h * 20;
      float4 w0 = *(const float4*)(wp);
      float4 w1 = *(const float4*)(wp + 4);
      float4 w2 = *(const float4*)(wp + 8);
      float4 w3 = *(const float4*)(wp + 12);
      float wv[16] = {w0.x, w0.y, w0.z, w0.w, w1.x, w1.y, w1.z, w1.w,
                      w2.x, w2.y, w2.z, w2.w, w3.x, w3.y, w3.z, w3.w};
#pragma unroll
      for (int d = 0; d < 16; ++d) {
        qa[0][d] += xv.x * wv[d];
        qa[1][d] += xv.y * wv[d];
      }
    }
    __syncthreads();
  }

  // ---- Phase B: bias + rope + elu+1 + (q'C)*z -> O^T in LDS ----
  {
    float bqf[16];
    float4 b0 = *(const float4*)(bq + h * 16);
    float4 b1 = *(const float4*)(bq + h * 16 + 4);
    float4 b2 = *(const float4*)(bq + h * 16 + 8);
    float4 b3 = *(const float4*)(bq + h * 16 + 12);
    bqf[0] = b0.x; bqf[1] = b0.y; bqf[2] = b0.z; bqf[3] = b0.w;
    bqf[4] = b1.x; bqf[5] = b1.y; bqf[6] = b1.z; bqf[7] = b1.w;
    bqf[8] = b2.x; bqf[9] = b2.y; bqf[10] = b2.z; bqf[11] = b2.w;
    bqf[12] = b3.x; bqf[13] = b3.y; bqf[14] = b3.z; bqf[15] = b3.w;
#pragma unroll
    for (int i = 0; i < 2; ++i) {
      int r = r0 + i;
      float qp[16];
#pragma unroll
      for (int d = 0; d < 8; ++d) {
        float a = qa[i][d] + bqf[d];
        float bb = qa[i][d + 8] + bqf[d + 8];
        float cc = rc[r][d], ss = rs[r][d];
        float n1 = a * cc - bb * ss;
        float n2 = a * ss + bb * cc;
        qp[d]     = (n1 > 0.f) ? (n1 + 1.f) : __expf(n1);
        qp[d + 8] = (n2 > 0.f) ? (n2 + 1.f) : __expf(n2);
      }
      float zacc = 1e-6f;
#pragma unroll
      for (int d = 0; d < 16; ++d) zacc += qp[d] * ksums[h * 20 + d];
      float zinv = 1.0f / zacc;
      float o[16];
#pragma unroll
      for (int e = 0; e < 16; ++e) o[e] = 0.f;
#pragma unroll
      for (int d = 0; d < 16; ++d) {
        const float* cp = ctxs + h * 260 + d * 16;
        float4 c0v = *(const float4*)cp;
        float4 c1v = *(const float4*)(cp + 4);
        float4 c2v = *(const float4*)(cp + 8);
        float4 c3v = *(const float4*)(cp + 12);
        float qd = qp[d];
        o[0]  += qd * c0v.x; o[1]  += qd * c0v.y; o[2]  += qd * c0v.z; o[3]  += qd * c0v.w;
        o[4]  += qd * c1v.x; o[5]  += qd * c1v.y; o[6]  += qd * c1v.z; o[7]  += qd * c1v.w;
        o[8]  += qd * c2v.x; o[9]  += qd * c2v.y; o[10] += qd * c2v.z; o[11] += qd * c2v.w;
        o[12] += qd * c3v.x; o[13] += qd * c3v.y; o[14] += qd * c3v.z; o[15] += qd * c3v.w;
      }
#pragma unroll
      for (int e = 0; e < 16; ++e)
        otF[(e * 8 + h) * 68 + r] = o[e] * zinv;   // row perm m=e*8+h
    }
  }
  __syncthreads();

  // ---- Phase C: out = O @ Wo + bo (Wo rows staged with matching perm) ----
  const int tc = tid & 31, tr2 = tid >> 5;
  const int c0 = tc * 4, rr0 = tr2 * 8;
  float acc[8][4];
#pragma unroll
  for (int i = 0; i < 8; ++i)
#pragma unroll
    for (int j = 0; j < 4; ++j) acc[i][j] = 0.f;
  float* wos = wqs;  // [32][128]

#pragma unroll 1
  for (int kb = 0; kb < 4; ++kb) {
#pragma unroll
    for (int p = 0; p < 2; ++p) {
      int idx = tid + p * 256;
      int mm = idx >> 4, c8 = (idx & 15) * 8;
      int m = kb * 32 + mm;
      int jrow = (m & 7) * 16 + (m >> 3);      // inverse of m = e*8+h
      const float* pw = Wo + (size_t)jrow * 128 + c8;
      float4 a = *(const float4*)pw;
      float4 b4 = *(const float4*)(pw + 4);
      float* dst = wos + mm * 128 + c8;
      *(float4*)dst = a;
      *(float4*)(dst + 4) = b4;
    }
    __syncthreads();
#pragma unroll 8
    for (int mm = 0; mm < 32; ++mm) {
      const float* op = otF + (kb * 32 + mm) * 68 + rr0;
      float4 xa = *(const float4*)op;
      float4 xb = *(const float4*)(op + 4);
      float4 wv = *(const float4*)(wos + mm * 128 + c0);
      float xv[8] = {xa.x, xa.y, xa.z, xa.w, xb.x, xb.y, xb.z, xb.w};
#pragma unroll
      for (int i = 0; i < 8; ++i) {
        acc[i][0] += xv[i] * wv.x;
        acc[i][1] += xv[i] * wv.y;
        acc[i][2] += xv[i] * wv.z;
        acc[i][3] += xv[i] * wv.w;
      }
    }
    __syncthreads();
  }

  float4 bof = *(const float4*)(bo + c0);
#pragma unroll
  for (int i = 0; i < 8; ++i) {
    int row = row0 + rr0 + i;
    float4 st;
    st.x = acc[i][0] + bof.x; st.y = acc[i][1] + bof.y;
    st.z = acc[i][2] + bof.z; st.w = acc[i][3] + bof.w;
    *(float4*)(out + (size_t)row * 128 + c0) = st;
  }
}

extern "C" void kernel_launch(void* const* d_in, const int* in_sizes, int n_in,
                              void* d_out, int out_size, void* d_ws, size_t ws_size,
                              hipStream_t stream) {
  const float* x  = (const float*)d_in[0];
  const float* Wq = (const float*)d_in[1];
  const float* bq = (const float*)d_in[2];
  const float* Wk = (const float*)d_in[3];
  const float* bk = (const float*)d_in[4];
  const float* Wv = (const float*)d_in[5];
  const float* bv = (const float*)d_in[6];
  const float* Wo = (const float*)d_in[7];
  const float* bo = (const float*)d_in[8];
  float* out = (float*)d_out;

  float* wsf  = (float*)d_ws;
  float* ctx  = wsf;           // 16384 f
  float* ksum = wsf + 16384;   // 1024 f   (total ws use: 68 KB)

  k_init<<<68, 256, 0, stream>>>(ctx);
  k_kv_ctx<<<1024, 256, 0, stream>>>(x, Wk, bk, Wv, bv, ctx, ksum);
  k_q_attn_o<<<1024, 256, 0, stream>>>(x, Wq, bq, Wo, bo, ctx, ksum, out);
}

// Round 4
// 207.743 us; speedup vs baseline: 1.3717x; 1.3717x over previous
//
#include <hip/hip_runtime.h>
#include <hip/hip_bf16.h>

// LightningAttention MI355X — round 4: split-bf16 (hi+lo) MFMA everywhere => ~fp32 accuracy at matrix-core speed.
// B=8 T=8192 DM=128 H=8 Dh=16.
// Every MFMA operand pair (A,B) is computed as Ah*Bh + Al*Bh + Ah*Bl (drops only ~2^-18 lo*lo term).

typedef __attribute__((ext_vector_type(8))) short short8;   // 8 bf16 = 4 VGPR (MFMA A/B frag)
typedef __attribute__((ext_vector_type(4))) float floatx4;  // MFMA C/D frag

#define DEV __device__ __forceinline__
#define MFMA __builtin_amdgcn_mfma_f32_16x16x32_bf16

DEV unsigned short bfh(float f) {
  unsigned int x = __float_as_uint(f);
  x += 0x7fffu + ((x >> 16) & 1u);     // round-to-nearest-even
  return (unsigned short)(x >> 16);
}
DEV float bfdec(unsigned short u) { return __uint_as_float(((unsigned int)u) << 16); }
DEV void splitf(float f, unsigned short& h, unsigned short& l) {
  h = bfh(f);
  l = bfh(f - bfdec(h));               // exact residual, next 8 mantissa bits
}
DEV void split8(const float* p, short8& h8, short8& l8) {
  float4 a = *(const float4*)p;
  float4 b = *(const float4*)(p + 4);
  float v[8] = {a.x, a.y, a.z, a.w, b.x, b.y, b.z, b.w};
  union { short8 s; unsigned short u[8]; } H, L;
#pragma unroll
  for (int i = 0; i < 8; ++i) {
    unsigned short hh, ll;
    splitf(v[i], hh, ll);
    H.u[i] = hh; L.u[i] = ll;
  }
  h8 = H.s; l8 = L.s;
}

// ---------------- k_prep: weight transpose -> split bf16 + zero ctx/ksum ----------------
__global__ void k_prep(const float* __restrict__ Wq, const float* __restrict__ Wk,
                       const float* __restrict__ Wv, const float* __restrict__ Wo,
                       unsigned short* __restrict__ WTh, unsigned short* __restrict__ WTl,
                       float* __restrict__ ctxz) {
  int gid = blockIdx.x * 256 + threadIdx.x;
  if (gid < 8192) {               // 4 mats x 128 n x 16 k-groups of 8
    int mat = gid >> 11, r = gid & 2047, n = r >> 4, k0 = (r & 15) * 8;
    const float* W = (mat == 0) ? Wq : (mat == 1) ? Wk : (mat == 2) ? Wv : Wo;
    union { uint4 q; unsigned short u[8]; } oh, ol;
#pragma unroll
    for (int i = 0; i < 8; ++i) {
      unsigned short hh, ll;
      splitf(W[(size_t)(k0 + i) * 128 + n], hh, ll);
      oh.u[i] = hh; ol.u[i] = ll;
    }
    *(uint4*)&WTh[mat * 16384 + n * 128 + k0] = oh.q;
    *(uint4*)&WTl[mat * 16384 + n * 128 + k0] = ol.q;
  } else if (gid < 8192 + 17408) {
    ctxz[gid - 8192] = 0.0f;      // ctx (16384) + ksum (1024)
  }
}

DEV void stage_rope64(int tid, int t0, float rc[64][9], float rs[64][9]) {
#pragma unroll
  for (int p = 0; p < 2; ++p) {
    int idx = tid + p * 256;
    int r = idx >> 3, j = idx & 7;
    float invf = 1.0f / powf(10000.0f, (float)j * 0.125f);
    float s, c;
    sincosf((float)(t0 + r) * invf, &s, &c);
    rc[r][j] = c; rs[r][j] = s;
  }
}

// ---------------- kernel 1: kv GEMM + rope/elu(k) + ctx/ksum ----------------
__global__ __launch_bounds__(256) void k_kv_ctx(
    const float* __restrict__ x,
    const unsigned short* __restrict__ WTkh, const unsigned short* __restrict__ WTkl,
    const unsigned short* __restrict__ WTvh, const unsigned short* __restrict__ WTvl,
    const float* __restrict__ bk, const float* __restrict__ bv,
    float* __restrict__ ctx, float* __restrict__ ksum) {
  __shared__ float rc[64][9], rs[64][9];
  __shared__ unsigned short KTh[8 * 16 * 72], KTl[8 * 16 * 72];  // [head][d][t(64)+pad8]
  __shared__ unsigned short VTh[8 * 16 * 72], VTl[8 * 16 * 72];
  const int tid = threadIdx.x;
  const int row0 = blockIdx.x * 64;
  const int b = row0 >> 13;
  const int t0 = row0 & 8191;

  stage_rope64(tid, t0, rc, rs);

  const int l = tid & 63, w = tid >> 6;
  const int lane16 = l & 15, quad = l >> 4;
  const int n0 = w * 64;                       // wave's 64 cols of [k(128)|v(128)]
  const bool isk = (n0 < 128);

  floatx4 acc[4][4];                           // [nt][mt]
#pragma unroll
  for (int i = 0; i < 4; ++i)
#pragma unroll
    for (int j = 0; j < 4; ++j) acc[i][j] = (floatx4){0.f, 0.f, 0.f, 0.f};

  // GEMM: D[m=t][n=col]; A = x rows (split in regs), B = WT rows (split, precomputed)
#pragma unroll
  for (int ks = 0; ks < 4; ++ks) {
    short8 afh[4], afl[4];
#pragma unroll
    for (int mt = 0; mt < 4; ++mt)
      split8(x + (size_t)(row0 + mt * 16 + lane16) * 128 + ks * 32 + quad * 8, afh[mt], afl[mt]);
#pragma unroll
    for (int nt = 0; nt < 4; ++nt) {
      int col = n0 + nt * 16 + lane16;
      const unsigned short* wph = (col < 128) ? (WTkh + (size_t)col * 128)
                                              : (WTvh + (size_t)(col - 128) * 128);
      const unsigned short* wpl = (col < 128) ? (WTkl + (size_t)col * 128)
                                              : (WTvl + (size_t)(col - 128) * 128);
      short8 bh = *(const short8*)(wph + ks * 32 + quad * 8);
      short8 bl = *(const short8*)(wpl + ks * 32 + quad * 8);
#pragma unroll
      for (int mt = 0; mt < 4; ++mt) {
        acc[nt][mt] = MFMA(afh[mt], bh, acc[nt][mt], 0, 0, 0);
        acc[nt][mt] = MFMA(afl[mt], bh, acc[nt][mt], 0, 0, 0);
        acc[nt][mt] = MFMA(afh[mt], bl, acc[nt][mt], 0, 0, 0);
      }
    }
  }

  // bias (lane = col)
#pragma unroll
  for (int nt = 0; nt < 4; ++nt) {
    int col = n0 + nt * 16 + lane16;
    float bias = isk ? bk[col] : bv[col - 128];
#pragma unroll
    for (int mt = 0; mt < 4; ++mt)
#pragma unroll
      for (int r = 0; r < 4; ++r) acc[nt][mt][r] += bias;
  }
  __syncthreads();   // rope tables ready

  // rope + elu+1 on k waves. C-layout: lane=d, row t = mt*16 + quad*4 + r.
  if (isk) {
    const int d = lane16, j = d & 7;
#pragma unroll
    for (int mt = 0; mt < 4; ++mt) {
      float cc[4], ss[4];
#pragma unroll
      for (int r = 0; r < 4; ++r) {
        int tl = mt * 16 + quad * 4 + r;
        cc[r] = rc[tl][j]; ss[r] = rs[tl][j];
      }
#pragma unroll
      for (int nt = 0; nt < 4; ++nt) {
#pragma unroll
        for (int r = 0; r < 4; ++r) {
          float v = acc[nt][mt][r];
          float p = __shfl_xor(v, 8);          // pair (d, d+8) within head
          float nv = (d < 8) ? (v * cc[r] - p * ss[r]) : (p * ss[r] + v * cc[r]);
          acc[nt][mt][r] = (nv > 0.f) ? (nv + 1.f) : __expf(nv);
        }
      }
    }
    // ksum[h][d]
#pragma unroll
    for (int nt = 0; nt < 4; ++nt) {
      float s = 0.f;
#pragma unroll
      for (int mt = 0; mt < 4; ++mt)
#pragma unroll
        for (int r = 0; r < 4; ++r) s += acc[nt][mt][r];
      s += __shfl_xor(s, 16);
      s += __shfl_xor(s, 32);
      if (l < 16) {
        int h = (n0 >> 4) + nt;
        atomicAdd(&ksum[(b * 8 + h) * 16 + d], s);
      }
    }
  }

  // pack C-layout -> [col][t] split bf16
  unsigned short* DH = isk ? KTh : VTh;
  unsigned short* DL = isk ? KTl : VTl;
#pragma unroll
  for (int nt = 0; nt < 4; ++nt) {
    int hh = ((n0 + nt * 16) >> 4) & 7;
#pragma unroll
    for (int mt = 0; mt < 4; ++mt) {
      union { uint2 q; unsigned short u[4]; } oh, ol;
#pragma unroll
      for (int r = 0; r < 4; ++r) splitf(acc[nt][mt][r], oh.u[r], ol.u[r]);
      int off = (hh * 16 + lane16) * 72 + mt * 16 + quad * 4;
      *(uint2*)&DH[off] = oh.q;
      *(uint2*)&DL[off] = ol.q;
    }
  }
  __syncthreads();

  // ctx[h] += K_h^T V_h (contraction over t, K=64 -> 2x3 MFMA)
#pragma unroll
  for (int hp = 0; hp < 2; ++hp) {
    int h = w * 2 + hp;
    floatx4 c = (floatx4){0.f, 0.f, 0.f, 0.f};
#pragma unroll
    for (int ks2 = 0; ks2 < 2; ++ks2) {
      int off = (h * 16 + lane16) * 72 + ks2 * 32 + quad * 8;
      short8 ah = *(const short8*)&KTh[off];
      short8 al = *(const short8*)&KTl[off];
      short8 vh = *(const short8*)&VTh[off];
      short8 vl = *(const short8*)&VTl[off];
      c = MFMA(ah, vh, c, 0, 0, 0);
      c = MFMA(al, vh, c, 0, 0, 0);
      c = MFMA(ah, vl, c, 0, 0, 0);
    }
#pragma unroll
    for (int r = 0; r < 4; ++r)
      atomicAdd(&ctx[((size_t)(b * 8 + h) * 16 + quad * 4 + r) * 16 + lane16], c[r]);
  }
}

// ---------------- kernel 2: q^T GEMM + rope/elu + apply MFMA + @Wo ----------------
__global__ __launch_bounds__(256) void k_q_out(
    const float* __restrict__ x,
    const unsigned short* __restrict__ WTqh, const unsigned short* __restrict__ WTql,
    const unsigned short* __restrict__ WToh, const unsigned short* __restrict__ WTol,
    const float* __restrict__ bq, const float* __restrict__ bo,
    const float* __restrict__ ctx, const float* __restrict__ ksum,
    float* __restrict__ out) {
  __shared__ float rc[64][9], rs[64][9];
  __shared__ unsigned short QOh[64 * 136], QOl[64 * 136];  // QQ then (aliased) OO; rows wave-private
  __shared__ unsigned short CTh[8 * 16 * 40], CTl[8 * 16 * 40];
  __shared__ float ksumS[128], bqS[128], boS[128];
  const int tid = threadIdx.x;
  const int row0 = blockIdx.x * 64;
  const int b = row0 >> 13;
  const int t0 = row0 & 8191;

  stage_rope64(tid, t0, rc, rs);
  if (tid < 128) {   // CT[h][e][p*16+d] = ctx[h][d][e], other 16-half zero (p = h&1)
    int h = tid >> 4, e = tid & 15, p = h & 1;
    unsigned int base = (h * 16 + e) * 40;
    union { uint4 q; unsigned int u[4]; } z0; z0.u[0] = z0.u[1] = z0.u[2] = z0.u[3] = 0;
    *(uint4*)&CTh[base + (1 - p) * 16] = z0.q;
    *(uint4*)&CTh[base + (1 - p) * 16 + 8] = z0.q;
    *(uint4*)&CTl[base + (1 - p) * 16] = z0.q;
    *(uint4*)&CTl[base + (1 - p) * 16 + 8] = z0.q;
    const float* cp = ctx + (size_t)(b * 8 + h) * 256 + e;
    union { uint4 q; unsigned short u[8]; } ch, cl;
#pragma unroll
    for (int d = 0; d < 8; ++d) splitf(cp[d * 16], ch.u[d], cl.u[d]);
    *(uint4*)&CTh[base + p * 16] = ch.q;
    *(uint4*)&CTl[base + p * 16] = cl.q;
#pragma unroll
    for (int d = 0; d < 8; ++d) splitf(cp[(8 + d) * 16], ch.u[d], cl.u[d]);
    *(uint4*)&CTh[base + p * 16 + 8] = ch.q;
    *(uint4*)&CTl[base + p * 16 + 8] = cl.q;
  } else {
    int t2 = tid - 128;
    ksumS[t2] = ksum[b * 128 + t2];
    bqS[t2] = bq[t2];
    boS[t2] = bo[t2];
  }
  __syncthreads();

  const int l = tid & 63, w = tid >> 6;
  const int lane16 = l & 15, quad = l >> 4;
  const int trow = row0 + w * 16 + lane16;     // wave's t rows (lane = t)
  const int tl = w * 16 + lane16;              // local t

  // ---- Phase A: q^T: D[m=qcol][n=t]; A = WTq rows, B = x rows (split) ----
  short8 xbh[4], xbl[4];
#pragma unroll
  for (int ks = 0; ks < 4; ++ks)
    split8(x + (size_t)trow * 128 + ks * 32 + quad * 8, xbh[ks], xbl[ks]);
  floatx4 qacc[8];
#pragma unroll
  for (int i = 0; i < 8; ++i) qacc[i] = (floatx4){0.f, 0.f, 0.f, 0.f};
#pragma unroll
  for (int mt = 0; mt < 8; ++mt) {
#pragma unroll
    for (int ks = 0; ks < 4; ++ks) {
      size_t off = (size_t)(mt * 16 + lane16) * 128 + ks * 32 + quad * 8;
      short8 afh = *(const short8*)(WTqh + off);
      short8 afl = *(const short8*)(WTql + off);
      qacc[mt] = MFMA(afh, xbh[ks], qacc[mt], 0, 0, 0);
      qacc[mt] = MFMA(afl, xbh[ks], qacc[mt], 0, 0, 0);
      qacc[mt] = MFMA(afh, xbl[ks], qacc[mt], 0, 0, 0);
    }
  }

  // ---- Phase B: bias + rope + elu+1 + z (in regs); pack QQ[t][d] split ----
  float cc[4], ss[4];
#pragma unroll
  for (int r = 0; r < 4; ++r) {                // d = quad*4+r; j = (quad&1)*4+r
    cc[r] = rc[tl][(quad & 1) * 4 + r];
    ss[r] = rs[tl][(quad & 1) * 4 + r];
  }
  float zi[8];
#pragma unroll
  for (int h = 0; h < 8; ++h) {
    float qp[4];
#pragma unroll
    for (int r = 0; r < 4; ++r) {
      float v = qacc[h][r] + bqS[h * 16 + quad * 4 + r];
      float p = __shfl_xor(v, 32);             // pair (d, d+8): quad ^ 2
      float nv = (quad < 2) ? (v * cc[r] - p * ss[r]) : (p * ss[r] + v * cc[r]);
      qp[r] = (nv > 0.f) ? (nv + 1.f) : __expf(nv);
    }
    float zp = 0.f;
#pragma unroll
    for (int r = 0; r < 4; ++r) zp += qp[r] * ksumS[h * 16 + quad * 4 + r];
    zp += __shfl_xor(zp, 16);
    zp += __shfl_xor(zp, 32);
    zi[h] = 1.0f / (zp + 1e-6f);
    union { uint2 q; unsigned short u[4]; } oh, ol;
#pragma unroll
    for (int r = 0; r < 4; ++r) splitf(qp[r], oh.u[r], ol.u[r]);
    int off = tl * 136 + h * 16 + quad * 4;
    *(uint2*)&QOh[off] = oh.q;
    *(uint2*)&QOl[off] = ol.q;
  }
  __syncthreads();

  // ---- Phase C: apply: D2[m=e][n=t] = C_h^T(padded) @ q'^T; keep o in regs ----
  float of[8][4];
#pragma unroll
  for (int h = 0; h < 8; ++h) {
    int ca = (h * 16 + lane16) * 40 + quad * 8;
    int qa = tl * 136 + (h >> 1) * 32 + quad * 8;
    short8 avh = *(const short8*)&CTh[ca];
    short8 avl = *(const short8*)&CTl[ca];
    short8 bvh = *(const short8*)&QOh[qa];
    short8 bvl = *(const short8*)&QOl[qa];
    floatx4 o = (floatx4){0.f, 0.f, 0.f, 0.f};
    o = MFMA(avh, bvh, o, 0, 0, 0);
    o = MFMA(avl, bvh, o, 0, 0, 0);
    o = MFMA(avh, bvl, o, 0, 0, 0);
#pragma unroll
    for (int r = 0; r < 4; ++r) of[h][r] = o[r] * zi[h];
  }
  __syncthreads();   // QQ dead; reuse as OO

#pragma unroll
  for (int h = 0; h < 8; ++h) {
    union { uint2 q; unsigned short u[4]; } oh, ol;
#pragma unroll
    for (int r = 0; r < 4; ++r) splitf(of[h][r], oh.u[r], ol.u[r]);
    int off = tl * 136 + h * 16 + quad * 4;
    *(uint2*)&QOh[off] = oh.q;
    *(uint2*)&QOl[off] = ol.q;
  }
  __syncthreads();

  // ---- Phase D: out = OO @ Wo + bo: D[m=t][n=oc] ----
  short8 oah[4], oal[4];
#pragma unroll
  for (int ks = 0; ks < 4; ++ks) {
    int off = tl * 136 + ks * 32 + quad * 8;
    oah[ks] = *(const short8*)&QOh[off];
    oal[ks] = *(const short8*)&QOl[off];
  }
  floatx4 oacc[8];
#pragma unroll
  for (int i = 0; i < 8; ++i) oacc[i] = (floatx4){0.f, 0.f, 0.f, 0.f};
#pragma unroll
  for (int nt = 0; nt < 8; ++nt) {
#pragma unroll
    for (int ks = 0; ks < 4; ++ks) {
      size_t off = (size_t)(nt * 16 + lane16) * 128 + ks * 32 + quad * 8;
      short8 wbh = *(const short8*)(WToh + off);
      short8 wbl = *(const short8*)(WTol + off);
      oacc[nt] = MFMA(oah[ks], wbh, oacc[nt], 0, 0, 0);
      oacc[nt] = MFMA(oal[ks], wbh, oacc[nt], 0, 0, 0);
      oacc[nt] = MFMA(oah[ks], wbl, oacc[nt], 0, 0, 0);
    }
  }
#pragma unroll
  for (int nt = 0; nt < 8; ++nt) {
    int oc = nt * 16 + lane16;
    float bb = boS[oc];
#pragma unroll
    for (int r = 0; r < 4; ++r) {
      int t = row0 + w * 16 + quad * 4 + r;
      out[(size_t)t * 128 + oc] = oacc[nt][r] + bb;
    }
  }
}

extern "C" void kernel_launch(void* const* d_in, const int* in_sizes, int n_in,
                              void* d_out, int out_size, void* d_ws, size_t ws_size,
                              hipStream_t stream) {
  const float* x  = (const float*)d_in[0];
  const float* Wq = (const float*)d_in[1];
  const float* bq = (const float*)d_in[2];
  const float* Wk = (const float*)d_in[3];
  const float* bk = (const float*)d_in[4];
  const float* Wv = (const float*)d_in[5];
  const float* bv = (const float*)d_in[6];
  const float* Wo = (const float*)d_in[7];
  const float* bo = (const float*)d_in[8];
  float* out = (float*)d_out;

  unsigned short* WTh = (unsigned short*)d_ws;         // 4 x 16384 bf16 hi = 128 KB
  unsigned short* WTl = WTh + 65536;                   // 4 x 16384 bf16 lo = 128 KB
  float* ctx  = (float*)((char*)d_ws + 262144);        // 16384 f
  float* ksum = ctx + 16384;                           // 1024 f   (total ws ~326 KB)

  k_prep<<<100, 256, 0, stream>>>(Wq, Wk, Wv, Wo, WTh, WTl, ctx);
  k_kv_ctx<<<1024, 256, 0, stream>>>(x, WTh + 16384, WTl + 16384, WTh + 32768, WTl + 32768,
                                     bk, bv, ctx, ksum);
  k_q_out<<<1024, 256, 0, stream>>>(x, WTh, WTl, WTh + 49152, WTl + 49152,
                                    bq, bo, ctx, ksum, out);
}